// Round 3
// baseline (303.683 us; speedup 1.0000x reference)
//
#include <hip/hip_runtime.h>

// out[128,16384] = [A|B](128x8384) @ [x; x2](8384x16384), bf16 MFMA.
// Round 3 vs round 2:
//  - xt stored transposed xt[r][n]: gen reads are lane-consecutive -> no bank conflicts
//  - A-fragments read directly from global wt (L2-resident, unswizzled), reg-prefetched
//  - x2 tile double-buffered -> ONE __syncthreads per K-step
//  - gen fast path: uniform-i octets read 9 LDS values instead of 16

constexpr int N_     = 128;
constexpr int S_     = 8256;
constexpr int BATCH_ = 16384;
constexpr int NKT    = 131;          // 8384 / 64
constexpr int X2_LD  = 72;           // x2 row stride (16B aligned, even bank spread)
constexpr int X2SZ   = 64 * X2_LD;
constexpr size_t WT_BYTES  = (size_t)NKT * 8192 * 2;   // 2,146,304
constexpr size_t PAIRS_OFF = WT_BYTES;

typedef __attribute__((ext_vector_type(8))) short short8;
typedef __attribute__((ext_vector_type(4))) float f32x4;

__device__ __forceinline__ float bf2f(ushort h) {
    unsigned u = (unsigned)h << 16;
    float f;
    __builtin_memcpy(&f, &u, 4);
    return f;
}
__device__ __forceinline__ ushort f2bf(float f) {
    unsigned u;
    __builtin_memcpy(&u, &f, 4);
    u = (u + 0x7FFFu + ((u >> 16) & 1u)) >> 16;   // RNE
    return (ushort)u;
}

// ---------------- phase 1a: triu pair table: pairs[s] = i | (j<<8) ----------------
__global__ void build_pairs(ushort* __restrict__ pairs) {
    int s = blockIdx.x * 256 + threadIdx.x;
    if (s >= S_) return;
    double d = 257.0 * 257.0 - 8.0 * (double)s;
    int i = (int)((257.0 - sqrt(d)) * 0.5);
    if (i < 0) i = 0;
    if (i > 127) i = 127;
    while (i < 127 && (i + 1) * (257 - (i + 1)) / 2 <= s) ++i;
    while (i > 0 && i * (257 - i) / 2 > s) --i;
    int j = i + (s - i * (257 - i) / 2);
    pairs[s] = (ushort)(i | (j << 8));
}

// ---------------- phase 1b: W -> bf16, K-tiled (UNswizzled) ----------------
// wt[kt*8192 + m*64 + kl] = bf16( W[m][kt*64 + kl] ),  W = [A | B]
__global__ void build_wt(const float* __restrict__ A, const float* __restrict__ B,
                         ushort* __restrict__ wt) {
    int e  = blockIdx.x * 256 + threadIdx.x;   // 131*8192 = 4192*256 exactly
    int kt = e >> 13;
    int p  = e & 8191;
    int m  = p >> 6;
    int kl = p & 63;
    int k  = kt * 64 + kl;
    float v = (k < 128) ? A[m * 128 + k] : B[(size_t)m * S_ + (k - 128)];
    wt[e] = f2bf(v);
}

// A-operand fragments for step kt, straight from L2-resident wt.
// af[kk*4+mt] holds A[m = wm*64+mt*16+l16][k = kt*64 + kk*32 + quad*8 .. +7]
__device__ __forceinline__ void load_af(short8 af[8], const ushort* __restrict__ wt,
                                        int kt, int wm, int l16, int quad) {
    const ushort* base = wt + (size_t)kt * 8192 + quad * 8;
    #pragma unroll
    for (int kk = 0; kk < 2; ++kk)
        #pragma unroll
        for (int mt = 0; mt < 4; ++mt) {
            const int m = wm * 64 + mt * 16 + l16;
            af[kk * 4 + mt] = *(const short8*)(base + m * 64 + kk * 32);
        }
}

// ---------------- phase 2: fused MFMA GEMM ----------------
// grid 256 (batch tiles of 64), 256 threads = 4 waves, tile 128x64,
// wave tile 64x32 (4x2 frags of 16x16x32), BK=64.
__global__ __launch_bounds__(256) void gemm_mfma(
    const float*  __restrict__ x,
    const ushort* __restrict__ wt,
    const ushort* __restrict__ pairs,
    float* __restrict__ out)
{
    __shared__ ushort xt[128 * 64];     // xt[r*64+n] = bf16 x[r][b0+n], 16 KB
    __shared__ ushort x2l[2 * X2SZ];    // x2 tile, double-buffered, 18 KB

    const int t    = threadIdx.x;
    const int b0   = blockIdx.x * 64;
    const int lane = t & 63;
    const int w    = t >> 6;
    const int wm   = w >> 1, wn = w & 1;
    const int l16  = lane & 15, quad = lane >> 4;
    const int n    = t & 63;            // gen: column owned by this thread
    const int krb  = w;                 // gen: k-octet base (wave index)

    // ---- stage xt (transposed), float4 global loads ----
    #pragma unroll
    for (int it = 0; it < 8; ++it) {
        const int idx = it * 256 + t;          // float4 index
        const int r  = idx >> 4;               // 16 float4 per row of 64
        const int c4 = (idx & 15) << 2;
        const float4 v = *(const float4*)&x[(size_t)r * BATCH_ + b0 + c4];
        uint2 pk;
        pk.x = (uint)f2bf(v.x) | ((uint)f2bf(v.y) << 16);
        pk.y = (uint)f2bf(v.z) | ((uint)f2bf(v.w) << 16);
        *(uint2*)&xt[r * 64 + c4] = pk;
    }
    __syncthreads();

    f32x4 acc[4][2];
    #pragma unroll
    for (int mt = 0; mt < 4; ++mt)
        #pragma unroll
        for (int nt = 0; nt < 2; ++nt)
            acc[mt][nt] = (f32x4){0.f, 0.f, 0.f, 0.f};

    short8 afc[8];
    load_af(afc, wt, 0, wm, l16, quad);

    for (int kt = 0; kt < NKT; ++kt) {
        ushort* xb = x2l + (kt & 1) * X2SZ;

        // ---- prefetch next step's A-frags (regs; latency hidden behind gen) ----
        short8 afn[8];
        if (kt + 1 < NKT) load_af(afn, wt, kt + 1, wm, l16, quad);

        // ---- generate x2 tile into xb ----
        const int kbase = kt * 64;
        if (kbase >= 128) {
            const int sb = kbase - 128;
            #pragma unroll
            for (int p = 0; p < 2; ++p) {
                const int kr = krb + p * 4;
                const uint4 pk = *(const uint4*)(pairs + sb + kr * 8);
                const uint pr[4] = {pk.x, pk.y, pk.z, pk.w};
                float prods[8];
                const uint i0 = pr[0] & 0xFFu;
                const uint i7 = (pr[3] >> 16) & 0xFFu;
                if (i0 == i7) {                       // wave-uniform fast path
                    const float xi = bf2f(xt[i0 * 64 + n]);
                    #pragma unroll
                    for (int e = 0; e < 8; ++e) {
                        const uint ent = (pr[e >> 1] >> ((e & 1) * 16)) & 0xFFFFu;
                        prods[e] = xi * bf2f(xt[(ent >> 8) * 64 + n]);
                    }
                } else {
                    #pragma unroll
                    for (int e = 0; e < 8; ++e) {
                        const uint ent = (pr[e >> 1] >> ((e & 1) * 16)) & 0xFFFFu;
                        prods[e] = bf2f(xt[(ent & 0xFFu) * 64 + n]) *
                                   bf2f(xt[(ent >> 8) * 64 + n]);
                    }
                }
                uint4 wv;
                wv.x = (uint)f2bf(prods[0]) | ((uint)f2bf(prods[1]) << 16);
                wv.y = (uint)f2bf(prods[2]) | ((uint)f2bf(prods[3]) << 16);
                wv.z = (uint)f2bf(prods[4]) | ((uint)f2bf(prods[5]) << 16);
                wv.w = (uint)f2bf(prods[6]) | ((uint)f2bf(prods[7]) << 16);
                *(uint4*)&xb[n * X2_LD + kr * 8] = wv;
            }
        } else {
            // k < 128: rows of [x; x2] are x itself
            #pragma unroll
            for (int p = 0; p < 2; ++p) {
                const int kr = krb + p * 4;
                uint4 wv;
                ushort e0 = xt[(kbase + kr * 8 + 0) * 64 + n];
                ushort e1 = xt[(kbase + kr * 8 + 1) * 64 + n];
                ushort e2 = xt[(kbase + kr * 8 + 2) * 64 + n];
                ushort e3 = xt[(kbase + kr * 8 + 3) * 64 + n];
                ushort e4 = xt[(kbase + kr * 8 + 4) * 64 + n];
                ushort e5 = xt[(kbase + kr * 8 + 5) * 64 + n];
                ushort e6 = xt[(kbase + kr * 8 + 6) * 64 + n];
                ushort e7 = xt[(kbase + kr * 8 + 7) * 64 + n];
                wv.x = (uint)e0 | ((uint)e1 << 16);
                wv.y = (uint)e2 | ((uint)e3 << 16);
                wv.z = (uint)e4 | ((uint)e5 << 16);
                wv.w = (uint)e6 | ((uint)e7 << 16);
                *(uint4*)&xb[n * X2_LD + kr * 8] = wv;
            }
        }

        __syncthreads();   // gen(kt) visible; prev MFMA done with other buffer

        // ---- MFMA over BK=64 (2 x K32) ----
        #pragma unroll
        for (int kk = 0; kk < 2; ++kk) {
            const int koff = kk * 32 + quad * 8;
            short8 bfr[2];
            #pragma unroll
            for (int nt = 0; nt < 2; ++nt) {
                const int nn = wn * 32 + nt * 16 + l16;
                bfr[nt] = *(const short8*)&xb[nn * X2_LD + koff];
            }
            #pragma unroll
            for (int mt = 0; mt < 4; ++mt)
                #pragma unroll
                for (int nt = 0; nt < 2; ++nt)
                    acc[mt][nt] = __builtin_amdgcn_mfma_f32_16x16x32_bf16(
                        afc[kk * 4 + mt], bfr[nt], acc[mt][nt], 0, 0, 0);
        }

        #pragma unroll
        for (int q = 0; q < 8; ++q) afc[q] = afn[q];
    }

    // ---- epilogue: C/D layout col=lane&15, row=quad*4+reg ----
    #pragma unroll
    for (int mt = 0; mt < 4; ++mt) {
        #pragma unroll
        for (int nt = 0; nt < 2; ++nt) {
            const int mbase = wm * 64 + mt * 16 + quad * 4;
            const size_t col = (size_t)b0 + wn * 32 + nt * 16 + l16;
            #pragma unroll
            for (int r = 0; r < 4; ++r)
                out[(size_t)(mbase + r) * BATCH_ + col] = acc[mt][nt][r];
        }
    }
}

extern "C" void kernel_launch(void* const* d_in, const int* in_sizes, int n_in,
                              void* d_out, int out_size, void* d_ws, size_t ws_size,
                              hipStream_t stream) {
    const float* x = (const float*)d_in[0];   // [128, 16384]
    const float* A = (const float*)d_in[1];   // [128, 128]
    const float* B = (const float*)d_in[2];   // [128, 8256]
    float* out = (float*)d_out;               // [128, 16384]

    ushort* wt    = (ushort*)d_ws;
    ushort* pairs = (ushort*)((char*)d_ws + PAIRS_OFF);

    build_pairs<<<(S_ + 255) / 256, 256, 0, stream>>>(pairs);
    build_wt<<<4192, 256, 0, stream>>>(A, B, wt);
    gemm_mfma<<<256, 256, 0, stream>>>(x, wt, pairs, out);
}

// Round 4
// 278.054 us; speedup vs baseline: 1.0922x; 1.0922x over previous
//
#include <hip/hip_runtime.h>

// out[128,16384] = [A|B](128x8384) @ [x; x2](8384x16384), bf16 MFMA.
// Round 4: barrier-free K-loop. K dimension PERMUTED so that every k-octet is:
//   - identity  (k' < 128):        B-frag = raw x octet (1 ds_read_b128)
//   - "nice"    (steps 2..123):    uniform i, j0 = 0 mod 8 -> 1 scalar + 1 b128
//   - ragged    (steps 124..130):  arbitrary pairs -> 16 scalar reads (7 steps only)
// B-fragments are generated IN REGISTERS per lane (no x2 LDS tile, no barriers).
// A-fragments read from L2-resident pre-packed wt (bf16, permuted K).

constexpr int N_     = 128;
constexpr int S_     = 8256;
constexpr int BATCH_ = 16384;
constexpr int KTOT   = 8384;         // 128 + 8256 = 131*64
constexpr int NKT    = 131;
constexpr int LD     = 136;          // xt row stride (ushorts): 68 dwords -> conflict-free
constexpr size_t WT_BYTES = (size_t)KTOT * 128 * 2;   // 2,146,304
constexpr size_t PP_OFF   = WT_BYTES;                 // perm-pair table offset

typedef __attribute__((ext_vector_type(8))) short short8;
typedef __attribute__((ext_vector_type(4))) float f32x4;

__device__ __forceinline__ float bf2f(ushort h) {
    unsigned u = (unsigned)h << 16;
    float f;
    __builtin_memcpy(&f, &u, 4);
    return f;
}
__device__ __forceinline__ ushort f2bf(float f) {
    unsigned u;
    __builtin_memcpy(&u, &f, 4);
    u = (u + 0x7FFFu + ((u >> 16) & 1u)) >> 16;   // RNE
    return (ushort)u;
}

// ---------- phase 1a: permuted pair table pp[k'] = i | (j<<8) ----------
// Region X    k'=[0,128):      pp = k' | 0xFF00          (identity: value x[k'])
// Region NICE k'=[128,7936):   976 octets, each uniform i, j0 = 8*jb, jb>=ceil(i/8)
// Region RAG  k'=[7936,8384):  448 leftover (i,j) with i <= j < 8*ceil(i/8)
__global__ void build_perm(ushort* __restrict__ pp) {
    int i = threadIdx.x;               // one thread per i, 128 threads
    if (i >= 128) return;
    pp[i] = (ushort)(i | (0xFFu << 8));
    int off_n = 0, off_r = 0;
    for (int q = 0; q < i; ++q) {
        off_n += 16 - ((q + 7) >> 3);
        off_r += (8 - (q & 7)) & 7;
    }
    const int jb0 = (i + 7) >> 3;
    int kb = 128 + off_n * 8;
    for (int jb = jb0; jb < 16; ++jb) {
        const int j0 = jb * 8;
        for (int e = 0; e < 8; ++e)
            pp[kb + (jb - jb0) * 8 + e] = (ushort)(i | ((j0 + e) << 8));
    }
    const int h = (8 - (i & 7)) & 7;
    const int rb = 7936 + off_r;
    for (int e = 0; e < h; ++e)
        pp[rb + e] = (ushort)(i | ((i + e) << 8));
}

// ---------- phase 1b: W -> bf16, K-tiled in PERMUTED order ----------
// wt[kt*8192 + m*64 + kl] = bf16( W[m][perm(kt*64+kl)] )
__global__ void build_wt(const float* __restrict__ A, const float* __restrict__ B,
                         const ushort* __restrict__ pp, ushort* __restrict__ wt) {
    int e  = blockIdx.x * 256 + threadIdx.x;   // 131*8192 = 4192*256 exactly
    int kt = e >> 13;
    int p  = e & 8191;
    int m  = p >> 6;
    int kl = p & 63;
    uint pr = pp[kt * 64 + kl];
    uint i = pr & 0xFFu, j = pr >> 8;
    float v;
    if (j == 0xFFu) v = A[m * 128 + i];
    else {
        int s = (int)(i * (257 - i) / 2 + (j - i));
        v = B[(size_t)m * S_ + s];
    }
    wt[e] = f2bf(v);
}

// ---------- phase 2: fused MFMA GEMM, barrier-free K-loop ----------
// grid 256 (batch tiles of 64), 4 waves, tile 128x64, wave tile 64x32 (4x2 frags).
__global__ __launch_bounds__(256) void gemm_mfma(
    const float*  __restrict__ x,
    const ushort* __restrict__ wt,
    const ushort* __restrict__ pp,
    float* __restrict__ out)
{
    __shared__ ushort xt[64 * LD];     // xt[n*LD + r] = bf16 x[r][b0+n], 17.4 KB

    const int t    = threadIdx.x;
    const int b0   = blockIdx.x * 64;
    const int lane = t & 63;
    const int w    = t >> 6;
    const int wm   = w >> 1, wn = w & 1;
    const int l16  = lane & 15, quad = lane >> 4;

    // ---- stage xt (column-major per batch column) ----
    #pragma unroll
    for (int it = 0; it < 32; ++it) {
        const int idx = it * 256 + t;
        const int r = idx >> 6, n = idx & 63;   // lane==n -> coalesced read, 2-way LDS write
        xt[n * LD + r] = f2bf(x[(size_t)r * BATCH_ + b0 + n]);
    }
    __syncthreads();

    f32x4 acc[4][2];
    #pragma unroll
    for (int mt = 0; mt < 4; ++mt)
        #pragma unroll
        for (int nt = 0; nt < 2; ++nt)
            acc[mt][nt] = (f32x4){0.f, 0.f, 0.f, 0.f};

    const ushort* xr0 = xt + (wn * 32 + l16) * LD;        // nt=0 column row
    const ushort* xr1 = xr0 + 16 * LD;                    // nt=1 column row

    for (int kt = 0; kt < NKT; ++kt) {
        // ---- A-frags from L2-resident wt (issued first; waitcnt floats past gen) ----
        short8 af[8];
        {
            const ushort* ab = wt + (size_t)kt * 8192 + quad * 8;
            #pragma unroll
            for (int kk = 0; kk < 2; ++kk)
                #pragma unroll
                for (int mt = 0; mt < 4; ++mt)
                    af[kk * 4 + mt] =
                        *(const short8*)(ab + (wm * 64 + mt * 16 + l16) * 64 + kk * 32);
        }

        // ---- generate B-frags in registers ----
        short8 bfr[2][2];   // [kk][nt]
        #pragma unroll
        for (int kk = 0; kk < 2; ++kk) {
            const int k0 = kt * 64 + kk * 32 + quad * 8;
            const uint4 pk = *(const uint4*)(pp + k0);    // 8 pairs, wave-uniform per quad
            const uint p0 = pk.x & 0xFFFFu, p7 = pk.w >> 16;
            const uint i0 = p0 & 0xFFu, j0 = p0 >> 8;
            const uint i7 = p7 & 0xFFu, j7 = p7 >> 8;
            #pragma unroll
            for (int nt = 0; nt < 2; ++nt) {
                const ushort* xr = nt ? xr1 : xr0;
                if (j0 == 0xFFu) {
                    // identity octet: B-frag = raw bf16 x values
                    bfr[kk][nt] = *(const short8*)(xr + i0);
                } else if (i0 == i7 && j7 == j0 + 7) {
                    // nice octet: uniform i, aligned consecutive j (perm guarantees j0%8==0)
                    const float xi = bf2f(xr[i0]);
                    const short8 wnd = *(const short8*)(xr + j0);
                    short8 o;
                    #pragma unroll
                    for (int e = 0; e < 8; ++e)
                        o[e] = (short)f2bf(xi * bf2f((ushort)wnd[e]));
                    bfr[kk][nt] = o;
                } else {
                    // ragged octet (steps 124..130 only): generic gather
                    const uint pr4[4] = {pk.x, pk.y, pk.z, pk.w};
                    short8 o;
                    #pragma unroll
                    for (int e = 0; e < 8; ++e) {
                        const uint ent = (pr4[e >> 1] >> ((e & 1) * 16)) & 0xFFFFu;
                        o[e] = (short)f2bf(bf2f(xr[ent & 0xFFu]) * bf2f(xr[ent >> 8]));
                    }
                    bfr[kk][nt] = o;
                }
            }
        }

        // ---- MFMA ----
        #pragma unroll
        for (int kk = 0; kk < 2; ++kk)
            #pragma unroll
            for (int mt = 0; mt < 4; ++mt)
                #pragma unroll
                for (int nt = 0; nt < 2; ++nt)
                    acc[mt][nt] = __builtin_amdgcn_mfma_f32_16x16x32_bf16(
                        af[kk * 4 + mt], bfr[kk][nt], acc[mt][nt], 0, 0, 0);
    }

    // ---- epilogue: C/D layout col=lane&15, row=quad*4+reg (verified r2/r3) ----
    #pragma unroll
    for (int mt = 0; mt < 4; ++mt) {
        #pragma unroll
        for (int nt = 0; nt < 2; ++nt) {
            const int mbase = wm * 64 + mt * 16 + quad * 4;
            const size_t col = (size_t)b0 + wn * 32 + nt * 16 + l16;
            #pragma unroll
            for (int r = 0; r < 4; ++r)
                out[(size_t)(mbase + r) * BATCH_ + col] = acc[mt][nt][r];
        }
    }
}

extern "C" void kernel_launch(void* const* d_in, const int* in_sizes, int n_in,
                              void* d_out, int out_size, void* d_ws, size_t ws_size,
                              hipStream_t stream) {
    const float* x = (const float*)d_in[0];   // [128, 16384]
    const float* A = (const float*)d_in[1];   // [128, 128]
    const float* B = (const float*)d_in[2];   // [128, 8256]
    float* out = (float*)d_out;               // [128, 16384]

    ushort* wt = (ushort*)d_ws;
    ushort* pp = (ushort*)((char*)d_ws + PP_OFF);

    build_perm<<<1, 128, 0, stream>>>(pp);
    build_wt<<<4192, 256, 0, stream>>>(A, B, pp, wt);
    gemm_mfma<<<256, 256, 0, stream>>>(x, wt, pp, out);
}

// Round 5
// 211.975 us; speedup vs baseline: 1.4326x; 1.3117x over previous
//
#include <hip/hip_runtime.h>

// out[128,16384] = [A|B](128x8384) @ [x; x2](8384x16384), bf16 MFMA.
// Round 5 = round 4 (barrier-free K-loop, permuted K, register B-frag gen)
//           + SPLIT-K x4 for occupancy (1024 blocks = 4 blocks/CU = 16 waves/CU)
//           + atomic f32 accumulation into zeroed out.
// K permutation (consistent across wt and gen):
//   identity k'<128: B-frag = raw x octet; NICE [128,7936): uniform i, aligned j-octet;
//   RAGGED [7936,8384): generic gather (7 of 131 steps).

constexpr int N_     = 128;
constexpr int S_     = 8256;
constexpr int BATCH_ = 16384;
constexpr int KTOT   = 8384;         // 131*64
constexpr int NKT    = 131;
constexpr int NSPLIT = 4;            // split-K factor
constexpr int KPS    = 33;           // ceil(131/4); last split gets 32
constexpr int LD     = 136;          // xt row stride (ushorts), 16B-aligned rows
constexpr size_t WT_BYTES = (size_t)KTOT * 128 * 2;
constexpr size_t PP_OFF   = WT_BYTES;

typedef __attribute__((ext_vector_type(8))) short short8;
typedef __attribute__((ext_vector_type(4))) float f32x4;

__device__ __forceinline__ float bf2f(ushort h) {
    unsigned u = (unsigned)h << 16;
    float f;
    __builtin_memcpy(&f, &u, 4);
    return f;
}
__device__ __forceinline__ ushort f2bf(float f) {
    unsigned u;
    __builtin_memcpy(&u, &f, 4);
    u = (u + 0x7FFFu + ((u >> 16) & 1u)) >> 16;   // RNE
    return (ushort)u;
}

// ---------- phase 1a: permuted pair table pp[k'] = i | (j<<8) ----------
__global__ void build_perm(ushort* __restrict__ pp) {
    int i = threadIdx.x;
    if (i >= 128) return;
    pp[i] = (ushort)(i | (0xFFu << 8));
    int off_n = 0, off_r = 0;
    for (int q = 0; q < i; ++q) {
        off_n += 16 - ((q + 7) >> 3);
        off_r += (8 - (q & 7)) & 7;
    }
    const int jb0 = (i + 7) >> 3;
    int kb = 128 + off_n * 8;
    for (int jb = jb0; jb < 16; ++jb) {
        const int j0 = jb * 8;
        for (int e = 0; e < 8; ++e)
            pp[kb + (jb - jb0) * 8 + e] = (ushort)(i | ((j0 + e) << 8));
    }
    const int h = (8 - (i & 7)) & 7;
    const int rb = 7936 + off_r;
    for (int e = 0; e < h; ++e)
        pp[rb + e] = (ushort)(i | ((i + e) << 8));
}

// ---------- phase 1b: W -> bf16, K-tiled in PERMUTED order ----------
__global__ void build_wt(const float* __restrict__ A, const float* __restrict__ B,
                         const ushort* __restrict__ pp, ushort* __restrict__ wt) {
    int e  = blockIdx.x * 256 + threadIdx.x;   // 131*8192 = 4192*256 exactly
    int kt = e >> 13;
    int p  = e & 8191;
    int m  = p >> 6;
    int kl = p & 63;
    uint pr = pp[kt * 64 + kl];
    uint i = pr & 0xFFu, j = pr >> 8;
    float v;
    if (j == 0xFFu) v = A[m * 128 + i];
    else {
        int s = (int)(i * (257 - i) / 2 + (j - i));
        v = B[(size_t)m * S_ + s];
    }
    wt[e] = f2bf(v);
}

// ---------- phase 2: fused MFMA GEMM, barrier-free K-loop, split-K ----------
// grid (256 batch tiles, NSPLIT), 4 waves, tile 128x64, wave tile 64x32.
__global__ __launch_bounds__(256) void gemm_mfma(
    const float*  __restrict__ x,
    const ushort* __restrict__ wt,
    const ushort* __restrict__ pp,
    float* __restrict__ out)
{
    __shared__ ushort xt[64 * LD];     // xt[n*LD + r] = bf16 x[r][b0+n], 17 KB

    const int t    = threadIdx.x;
    const int b0   = blockIdx.x * 64;
    const int sp   = blockIdx.y;
    const int kt0  = sp * KPS;
    const int kt1  = (kt0 + KPS < NKT) ? (kt0 + KPS) : NKT;
    const int lane = t & 63;
    const int w    = t >> 6;
    const int wm   = w >> 1, wn = w & 1;
    const int l16  = lane & 15, quad = lane >> 4;

    // ---- stage xt ----
    #pragma unroll
    for (int it = 0; it < 32; ++it) {
        const int idx = it * 256 + t;
        const int r = idx >> 6, n = idx & 63;   // coalesced global read
        xt[n * LD + r] = f2bf(x[(size_t)r * BATCH_ + b0 + n]);
    }
    __syncthreads();

    f32x4 acc[4][2];
    #pragma unroll
    for (int mt = 0; mt < 4; ++mt)
        #pragma unroll
        for (int nt = 0; nt < 2; ++nt)
            acc[mt][nt] = (f32x4){0.f, 0.f, 0.f, 0.f};

    const ushort* xr0 = xt + (wn * 32 + l16) * LD;
    const ushort* xr1 = xr0 + 16 * LD;

    for (int kt = kt0; kt < kt1; ++kt) {
        // ---- A-frags from L2-resident wt ----
        short8 af[8];
        {
            const ushort* ab = wt + (size_t)kt * 8192 + quad * 8;
            #pragma unroll
            for (int kk = 0; kk < 2; ++kk)
                #pragma unroll
                for (int mt = 0; mt < 4; ++mt)
                    af[kk * 4 + mt] =
                        *(const short8*)(ab + (wm * 64 + mt * 16 + l16) * 64 + kk * 32);
        }

        // ---- generate B-frags in registers ----
        short8 bfr[2][2];
        #pragma unroll
        for (int kk = 0; kk < 2; ++kk) {
            const int k0 = kt * 64 + kk * 32 + quad * 8;
            const uint4 pk = *(const uint4*)(pp + k0);
            const uint p0 = pk.x & 0xFFFFu, p7 = pk.w >> 16;
            const uint i0 = p0 & 0xFFu, j0 = p0 >> 8;
            const uint i7 = p7 & 0xFFu, j7 = p7 >> 8;
            #pragma unroll
            for (int nt = 0; nt < 2; ++nt) {
                const ushort* xr = nt ? xr1 : xr0;
                if (j0 == 0xFFu) {
                    bfr[kk][nt] = *(const short8*)(xr + i0);
                } else if (i0 == i7 && j7 == j0 + 7) {
                    const float xi = bf2f(xr[i0]);
                    const short8 wnd = *(const short8*)(xr + j0);
                    short8 o;
                    #pragma unroll
                    for (int e = 0; e < 8; ++e)
                        o[e] = (short)f2bf(xi * bf2f((ushort)wnd[e]));
                    bfr[kk][nt] = o;
                } else {
                    const uint pr4[4] = {pk.x, pk.y, pk.z, pk.w};
                    short8 o;
                    #pragma unroll
                    for (int e = 0; e < 8; ++e) {
                        const uint ent = (pr4[e >> 1] >> ((e & 1) * 16)) & 0xFFFFu;
                        o[e] = (short)f2bf(bf2f(xr[ent & 0xFFu]) * bf2f(xr[ent >> 8]));
                    }
                    bfr[kk][nt] = o;
                }
            }
        }

        // ---- MFMA ----
        #pragma unroll
        for (int kk = 0; kk < 2; ++kk)
            #pragma unroll
            for (int mt = 0; mt < 4; ++mt)
                #pragma unroll
                for (int nt = 0; nt < 2; ++nt)
                    acc[mt][nt] = __builtin_amdgcn_mfma_f32_16x16x32_bf16(
                        af[kk * 4 + mt], bfr[kk][nt], acc[mt][nt], 0, 0, 0);
    }

    // ---- epilogue: atomic accumulate (C/D layout col=lane&15, row=quad*4+reg) ----
    #pragma unroll
    for (int mt = 0; mt < 4; ++mt) {
        #pragma unroll
        for (int nt = 0; nt < 2; ++nt) {
            const int mbase = wm * 64 + mt * 16 + quad * 4;
            const size_t col = (size_t)b0 + wn * 32 + nt * 16 + l16;
            #pragma unroll
            for (int r = 0; r < 4; ++r)
                unsafeAtomicAdd(&out[(size_t)(mbase + r) * BATCH_ + col],
                                acc[mt][nt][r]);
        }
    }
}

extern "C" void kernel_launch(void* const* d_in, const int* in_sizes, int n_in,
                              void* d_out, int out_size, void* d_ws, size_t ws_size,
                              hipStream_t stream) {
    const float* x = (const float*)d_in[0];   // [128, 16384]
    const float* A = (const float*)d_in[1];   // [128, 128]
    const float* B = (const float*)d_in[2];   // [128, 8256]
    float* out = (float*)d_out;               // [128, 16384]

    ushort* wt = (ushort*)d_ws;
    ushort* pp = (ushort*)((char*)d_ws + PP_OFF);

    hipMemsetAsync(out, 0, (size_t)N_ * BATCH_ * sizeof(float), stream);
    build_perm<<<1, 128, 0, stream>>>(pp);
    build_wt<<<4192, 256, 0, stream>>>(A, B, pp, wt);
    gemm_mfma<<<dim3(BATCH_ / 64, NSPLIT), 256, 0, stream>>>(x, wt, pp, out);
}